// Round 3
// baseline (213.092 us; speedup 1.0000x reference)
//
#include <hip/hip_runtime.h>

// PatchAttacker: B=32 images 512x512x3, N=6 boxes, patch 512x512x3.
// Final pixel = bilinear(patch) of the LAST valid covering patch box, else image.
// R3: same as R2 but with clang ext_vector float4 (HIP float4 is a class and
// is rejected by __builtin_nontemporal_*).

#define Nn 6
#define Hh 512
#define Ww 512
#define Pp 512

typedef float v4f __attribute__((ext_vector_type(4)));

__global__ __launch_bounds__(256) void patch_attack_kernel(
    const float* __restrict__ images,  // [B,H,W,3]
    const float* __restrict__ boxes,   // [B,N,4]
    const float* __restrict__ patch,   // [P,P,3]
    float* __restrict__ out)           // [B,H,W,3]
{
    __shared__ int      s_y0[Nn], s_x0[Nn], s_h[Nn];
    __shared__ unsigned s_w[Nn];
    __shared__ float    s_sy[Nn], s_sx[Nn];

    // 256 blocks per image (1024 px/block); b block-uniform
    const int b = blockIdx.x >> 8;

    if (threadIdx.x < Nn) {
        const int n = threadIdx.x;
        const float* bx = boxes + ((size_t)b * Nn + n) * 4;
        const float ymin = bx[0], xmin = bx[1], ymax = bx[2], xmax = bx[3];
        const float h  = ymax - ymin;
        const float w  = xmax - xmin;
        const float pw = h * 0.5f;            // SCALE
        const float ph = pw;                  // ASPECT = 1
        const float oy = ymin + h * 0.5f;
        const float ox = xmin + w * 0.5f;
        float yp = fmaxf(oy - ph * 0.5f, 0.0f);
        float xp = fmaxf(ox - pw * 0.5f, 0.0f);
        yp = (yp + ph > 512.0f) ? (512.0f - ph) : yp;
        xp = (xp + pw > 512.0f) ? (512.0f - pw) : xp;
        const bool valid = ph > 60.0f;        // MIN_PH
        const int hI = (int)ph;               // trunc casts, all >= 0
        const int wI = (int)pw;
        s_y0[n] = (int)yp;
        s_x0[n] = (int)xp;
        s_h[n]  = valid ? hI : 0;             // 0 => never hits
        s_w[n]  = (unsigned)wI;
        s_sy[n] = 512.0f / (float)(hI > 1 ? hI : 1);
        s_sx[n] = 512.0f / (float)(wI > 1 ? wI : 1);
    }
    __syncthreads();

    const int t    = blockIdx.x * 256 + threadIdx.x;
    const int pix0 = t << 2;                       // 4 px/thread
    const int rem  = pix0 & (Hh * Ww - 1);
    const int y    = rem >> 9;                     // wave-uniform (128 thr/row)
    const int x0   = rem & (Ww - 1);

    // per-box row-level state (amortized over 4 pixels)
    unsigned wEff[Nn];
    int   xo[Nn], offl[Nn], offh[Nn];
    float wyv[Nn], omwy[Nn], sxs[Nn];
    unsigned anyrow = 0;
    #pragma unroll
    for (int n = 0; n < Nn; ++n) {
        const int dy = y - s_y0[n];
        const bool rh = (unsigned)dy < (unsigned)s_h[n];
        wEff[n] = rh ? s_w[n] : 0u;
        anyrow |= wEff[n];
        xo[n]  = s_x0[n];
        sxs[n] = s_sx[n];
        float sy = ((float)dy + 0.5f) * s_sy[n] - 0.5f;
        sy = fminf(fmaxf(sy, 0.0f), 511.0f);
        const int yl = (int)sy;                    // floor (sy >= 0)
        const int yh = (yl + 1 < 511) ? (yl + 1) : 511;
        wyv[n]  = sy - (float)yl;
        omwy[n] = 1.0f - wyv[n];
        offl[n] = yl * (Pp * 3);
        offh[n] = yh * (Pp * 3);
    }

    float res[12];
    unsigned covmask = 0;

    if (anyrow) {                                  // wave-uniform branch
        #pragma unroll
        for (int j = 0; j < 4; ++j) {
            const int x = x0 + j;
            #pragma unroll
            for (int n = Nn - 1; n >= 0; --n) {    // descending = last writer
                const int dx = x - xo[n];
                if ((unsigned)dx < wEff[n]) {
                    float sx = ((float)dx + 0.5f) * sxs[n] - 0.5f;
                    sx = fminf(fmaxf(sx, 0.0f), 511.0f);
                    const int xl = (int)sx;
                    const int xh = (xl + 1 < 511) ? (xl + 1) : 511;
                    const float wx   = sx - (float)xl;
                    const float omwx = 1.0f - wx;
                    const float* __restrict__ rl = patch + offl[n];
                    const float* __restrict__ rh_ = patch + offh[n];
                    const int al = xl * 3, ah = xh * 3;
                    // separable bilinear, same op order as reference
                    res[j*3+0] = (rl[al+0]*omwy[n] + rh_[al+0]*wyv[n]) * omwx
                               + (rl[ah+0]*omwy[n] + rh_[ah+0]*wyv[n]) * wx;
                    res[j*3+1] = (rl[al+1]*omwy[n] + rh_[al+1]*wyv[n]) * omwx
                               + (rl[ah+1]*omwy[n] + rh_[ah+1]*wyv[n]) * wx;
                    res[j*3+2] = (rl[al+2]*omwy[n] + rh_[al+2]*wyv[n]) * omwx
                               + (rl[ah+2]*omwy[n] + rh_[ah+2]*wyv[n]) * wx;
                    covmask |= 1u << j;
                    break;
                }
            }
        }
    }

    if (covmask != 0xFu) {
        const v4f* __restrict__ ip = (const v4f*)(images + (size_t)pix0 * 3);
        const v4f i0 = __builtin_nontemporal_load(ip + 0);
        const v4f i1 = __builtin_nontemporal_load(ip + 1);
        const v4f i2 = __builtin_nontemporal_load(ip + 2);
        if (!(covmask & 1u)) { res[0] = i0.x; res[1]  = i0.y; res[2]  = i0.z; }
        if (!(covmask & 2u)) { res[3] = i0.w; res[4]  = i1.x; res[5]  = i1.y; }
        if (!(covmask & 4u)) { res[6] = i1.z; res[7]  = i1.w; res[8]  = i2.x; }
        if (!(covmask & 8u)) { res[9] = i2.y; res[10] = i2.z; res[11] = i2.w; }
    }

    v4f* __restrict__ op = (v4f*)(out + (size_t)pix0 * 3);
    v4f o0 = { res[0], res[1], res[2],  res[3] };
    v4f o1 = { res[4], res[5], res[6],  res[7] };
    v4f o2 = { res[8], res[9], res[10], res[11] };
    __builtin_nontemporal_store(o0, op + 0);
    __builtin_nontemporal_store(o1, op + 1);
    __builtin_nontemporal_store(o2, op + 2);
}

extern "C" void kernel_launch(void* const* d_in, const int* in_sizes, int n_in,
                              void* d_out, int out_size, void* d_ws, size_t ws_size,
                              hipStream_t stream) {
    const float* images = (const float*)d_in[0];
    const float* boxes  = (const float*)d_in[1];
    const float* patch  = (const float*)d_in[2];
    float* out = (float*)d_out;

    const int total_pixels = 32 * Hh * Ww;          // 8388608
    const int grid = total_pixels / (256 * 4);      // 8192 blocks, 4 px/thread

    patch_attack_kernel<<<grid, 256, 0, stream>>>(images, boxes, patch, out);
}

// Round 4
// 190.809 us; speedup vs baseline: 1.1168x; 1.1168x over previous
//
#include <hip/hip_runtime.h>

// PatchAttacker: B=32 images 512x512x3, N=6 boxes, patch 512x512x3.
// Final pixel = bilinear(patch) of the LAST valid covering patch box, else image.
// R4: R1's memory pattern (1 px/thread, 12 B/lane contiguous, cached stores,
// conditional image load) + R2's LDS box-geometry hoist cached in registers.

#define Nn 6
#define Hh 512
#define Ww 512
#define Pp 512

__global__ __launch_bounds__(256) void patch_attack_kernel(
    const float* __restrict__ images,  // [B,H,W,3]
    const float* __restrict__ boxes,   // [B,N,4]
    const float* __restrict__ patch,   // [P,P,3]
    float* __restrict__ out)           // [B,H,W,3]
{
    __shared__ int   s_y0[Nn], s_x0[Nn], s_h[Nn], s_w[Nn];
    __shared__ float s_sy[Nn], s_sx[Nn];

    // 1024 blocks per image (256 px/block); b block-uniform
    const int b = blockIdx.x >> 10;

    if (threadIdx.x < Nn) {
        const int n = threadIdx.x;
        const float* bx = boxes + ((size_t)b * Nn + n) * 4;
        const float ymin = bx[0], xmin = bx[1], ymax = bx[2], xmax = bx[3];
        const float h  = ymax - ymin;
        const float w  = xmax - xmin;
        const float pw = h * 0.5f;            // SCALE
        const float ph = pw;                  // ASPECT = 1
        const float oy = ymin + h * 0.5f;
        const float ox = xmin + w * 0.5f;
        float yp = fmaxf(oy - ph * 0.5f, 0.0f);
        float xp = fmaxf(ox - pw * 0.5f, 0.0f);
        yp = (yp + ph > 512.0f) ? (512.0f - ph) : yp;
        xp = (xp + pw > 512.0f) ? (512.0f - pw) : xp;
        const bool valid = ph > 60.0f;        // MIN_PH
        const int hI = (int)ph;               // trunc casts, all >= 0
        const int wI = (int)pw;
        s_y0[n] = (int)yp;
        s_x0[n] = (int)xp;
        s_h[n]  = valid ? hI : 0;             // 0 => never hits
        s_w[n]  = wI;
        s_sy[n] = 512.0f / (float)(hI > 1 ? hI : 1);
        s_sx[n] = 512.0f / (float)(wI > 1 ? wI : 1);
    }
    __syncthreads();

    // cache block-uniform box params in registers (one LDS read each)
    int   y0[Nn], x0[Nn], hh[Nn], ww[Nn];
    float syv[Nn], sxv[Nn];
    #pragma unroll
    for (int n = 0; n < Nn; ++n) {
        y0[n]  = s_y0[n];
        x0[n]  = s_x0[n];
        hh[n]  = s_h[n];
        ww[n]  = s_w[n];
        syv[n] = s_sy[n];
        sxv[n] = s_sx[n];
    }

    const int pix = blockIdx.x * 256 + threadIdx.x;
    const int rem = pix & (Hh * Ww - 1);
    const int y   = rem >> 9;                 // W = 512
    const int x   = rem & (Ww - 1);

    float r0, r1, r2;
    bool covered = false;

    // descending n: first valid covering box == last writer in the scan
    #pragma unroll
    for (int n = Nn - 1; n >= 0; --n) {
        const int dy = y - y0[n];
        const int dx = x - x0[n];
        if ((unsigned)dy < (unsigned)hh[n] && (unsigned)dx < (unsigned)ww[n]) {
            float sy = ((float)dy + 0.5f) * syv[n] - 0.5f;
            float sx = ((float)dx + 0.5f) * sxv[n] - 0.5f;
            sy = fminf(fmaxf(sy, 0.0f), 511.0f);
            sx = fminf(fmaxf(sx, 0.0f), 511.0f);
            const int yl = (int)sy;           // floor (sy >= 0)
            const int yh = (yl + 1 < 511) ? (yl + 1) : 511;
            const float wy = sy - (float)yl;
            const int xl = (int)sx;
            const int xh = (xl + 1 < 511) ? (xl + 1) : 511;
            const float wx = sx - (float)xl;
            const float omwy = 1.0f - wy;
            const float omwx = 1.0f - wx;

            const float* __restrict__ pll = patch + ((size_t)yl * Pp + xl) * 3;
            const float* __restrict__ plh = patch + ((size_t)yl * Pp + xh) * 3;
            const float* __restrict__ phl = patch + ((size_t)yh * Pp + xl) * 3;
            const float* __restrict__ phh = patch + ((size_t)yh * Pp + xh) * 3;
            // separable bilinear, same op order as reference
            r0 = (pll[0] * omwy + phl[0] * wy) * omwx + (plh[0] * omwy + phh[0] * wy) * wx;
            r1 = (pll[1] * omwy + phl[1] * wy) * omwx + (plh[1] * omwy + phh[1] * wy) * wx;
            r2 = (pll[2] * omwy + phl[2] * wy) * omwx + (plh[2] * omwy + phh[2] * wy) * wx;
            covered = true;
            break;
        }
    }

    if (!covered) {
        const float* __restrict__ ip = images + (size_t)pix * 3;
        r0 = ip[0];
        r1 = ip[1];
        r2 = ip[2];
    }

    float* __restrict__ op = out + (size_t)pix * 3;
    op[0] = r0;
    op[1] = r1;
    op[2] = r2;
}

extern "C" void kernel_launch(void* const* d_in, const int* in_sizes, int n_in,
                              void* d_out, int out_size, void* d_ws, size_t ws_size,
                              hipStream_t stream) {
    const float* images = (const float*)d_in[0];
    const float* boxes  = (const float*)d_in[1];
    const float* patch  = (const float*)d_in[2];
    float* out = (float*)d_out;

    const int total_pixels = 32 * Hh * Ww;      // 8388608
    const int block = 256;
    const int grid  = total_pixels / block;     // 32768

    patch_attack_kernel<<<grid, block, 0, stream>>>(images, boxes, patch, out);
}

// Round 5
// 190.669 us; speedup vs baseline: 1.1176x; 1.0007x over previous
//
#include <hip/hip_runtime.h>

// PatchAttacker: B=32 images 512x512x3, N=6 boxes, patch 512x512x3.
// Final pixel = bilinear(patch) of the LAST valid covering patch box, else image.
// R5: compute 1 px/thread into LDS (low-VALU path from R4), then re-emit all
// global traffic as contiguous 16 B/lane dwordx4 (192 threads x float4 per
// 256-px block). NT loads/stores for the streamed image/out (full lines, and
// keeps the 3 MB patch resident in L2). Image float4 skipped if fully covered.

#define Nn 6
#define Hh 512
#define Ww 512
#define Pp 512

typedef float v4f __attribute__((ext_vector_type(4)));

__global__ __launch_bounds__(256) void patch_attack_kernel(
    const float* __restrict__ images,  // [B,H,W,3]
    const float* __restrict__ boxes,   // [B,N,4]
    const float* __restrict__ patch,   // [P,P,3]
    float* __restrict__ out)           // [B,H,W,3]
{
    __shared__ int   s_y0[Nn], s_x0[Nn], s_h[Nn], s_w[Nn];
    __shared__ float s_sy[Nn], s_sx[Nn];
    __shared__ float s_res[256 * 3];          // per-pixel patch result
    __shared__ unsigned char s_cov[256];      // per-pixel coverage flag

    const int tid = threadIdx.x;
    // 1024 blocks per image (256 px/block); b block-uniform
    const int b = blockIdx.x >> 10;

    if (tid < Nn) {
        const int n = tid;
        const float* bx = boxes + ((size_t)b * Nn + n) * 4;
        const float ymin = bx[0], xmin = bx[1], ymax = bx[2], xmax = bx[3];
        const float h  = ymax - ymin;
        const float w  = xmax - xmin;
        const float pw = h * 0.5f;            // SCALE
        const float ph = pw;                  // ASPECT = 1
        const float oy = ymin + h * 0.5f;
        const float ox = xmin + w * 0.5f;
        float yp = fmaxf(oy - ph * 0.5f, 0.0f);
        float xp = fmaxf(ox - pw * 0.5f, 0.0f);
        yp = (yp + ph > 512.0f) ? (512.0f - ph) : yp;
        xp = (xp + pw > 512.0f) ? (512.0f - pw) : xp;
        const bool valid = ph > 60.0f;        // MIN_PH
        const int hI = (int)ph;               // trunc casts, all >= 0
        const int wI = (int)pw;
        s_y0[n] = (int)yp;
        s_x0[n] = (int)xp;
        s_h[n]  = valid ? hI : 0;             // 0 => never hits
        s_w[n]  = wI;
        s_sy[n] = 512.0f / (float)(hI > 1 ? hI : 1);
        s_sx[n] = 512.0f / (float)(wI > 1 ? wI : 1);
    }
    __syncthreads();

    // ---- phase 1: per-pixel patch evaluation into LDS ----
    const int pix = blockIdx.x * 256 + tid;
    const int rem = pix & (Hh * Ww - 1);
    const int y   = rem >> 9;                 // W = 512
    const int x   = rem & (Ww - 1);

    float r0 = 0.0f, r1 = 0.0f, r2 = 0.0f;
    bool covered = false;

    // descending n: first valid covering box == last writer in the scan
    #pragma unroll
    for (int n = Nn - 1; n >= 0; --n) {
        const int dy = y - s_y0[n];
        const int dx = x - s_x0[n];
        if ((unsigned)dy < (unsigned)s_h[n] && (unsigned)dx < (unsigned)s_w[n]) {
            float sy = ((float)dy + 0.5f) * s_sy[n] - 0.5f;
            float sx = ((float)dx + 0.5f) * s_sx[n] - 0.5f;
            sy = fminf(fmaxf(sy, 0.0f), 511.0f);
            sx = fminf(fmaxf(sx, 0.0f), 511.0f);
            const int yl = (int)sy;           // floor (sy >= 0)
            const int yh = (yl + 1 < 511) ? (yl + 1) : 511;
            const float wy = sy - (float)yl;
            const int xl = (int)sx;
            const int xh = (xl + 1 < 511) ? (xl + 1) : 511;
            const float wx = sx - (float)xl;
            const float omwy = 1.0f - wy;
            const float omwx = 1.0f - wx;

            const float* __restrict__ pll = patch + ((size_t)yl * Pp + xl) * 3;
            const float* __restrict__ plh = patch + ((size_t)yl * Pp + xh) * 3;
            const float* __restrict__ phl = patch + ((size_t)yh * Pp + xl) * 3;
            const float* __restrict__ phh = patch + ((size_t)yh * Pp + xh) * 3;
            // separable bilinear, same op order as reference
            r0 = (pll[0] * omwy + phl[0] * wy) * omwx + (plh[0] * omwy + phh[0] * wy) * wx;
            r1 = (pll[1] * omwy + phl[1] * wy) * omwx + (plh[1] * omwy + phh[1] * wy) * wx;
            r2 = (pll[2] * omwy + phl[2] * wy) * omwx + (plh[2] * omwy + phh[2] * wy) * wx;
            covered = true;
            break;
        }
    }

    s_res[tid * 3 + 0] = r0;                  // stride-3 dwords: 2-way bank alias (free)
    s_res[tid * 3 + 1] = r1;
    s_res[tid * 3 + 2] = r2;
    s_cov[tid] = covered ? 1 : 0;
    __syncthreads();

    // ---- phase 2: contiguous float4 global traffic (192 threads) ----
    if (tid < 192) {
        const int f0 = tid << 2;                              // float offset in block, 0..764
        const size_t gf = (size_t)blockIdx.x * 768 + f0;      // 16B-aligned
        const bool c0 = s_cov[(f0 + 0) / 3];
        const bool c1 = s_cov[(f0 + 1) / 3];
        const bool c2 = s_cov[(f0 + 2) / 3];
        const bool c3 = s_cov[(f0 + 3) / 3];
        v4f v = {0.0f, 0.0f, 0.0f, 0.0f};
        if (!(c0 && c1 && c2 && c3)) {
            v = __builtin_nontemporal_load((const v4f*)(images + gf));
        }
        v4f o;
        o.x = c0 ? s_res[f0 + 0] : v.x;
        o.y = c1 ? s_res[f0 + 1] : v.y;
        o.z = c2 ? s_res[f0 + 2] : v.z;
        o.w = c3 ? s_res[f0 + 3] : v.w;
        __builtin_nontemporal_store(o, (v4f*)(out + gf));
    }
}

extern "C" void kernel_launch(void* const* d_in, const int* in_sizes, int n_in,
                              void* d_out, int out_size, void* d_ws, size_t ws_size,
                              hipStream_t stream) {
    const float* images = (const float*)d_in[0];
    const float* boxes  = (const float*)d_in[1];
    const float* patch  = (const float*)d_in[2];
    float* out = (float*)d_out;

    const int total_pixels = 32 * Hh * Ww;      // 8388608
    const int block = 256;
    const int grid  = total_pixels / block;     // 32768

    patch_attack_kernel<<<grid, block, 0, stream>>>(images, boxes, patch, out);
}